// Round 11
// baseline (123.692 us; speedup 1.0000x reference)
//
#include <hip/hip_runtime.h>
#include <math.h>

#define T_LEN  65536
#define T_PAD  65792      // T + STEP
#define C_CH   64
#define STEP_  256
#define K_     257        // WS/2 + 1
#define NWV    8          // waves per block
#define FPI    16         // frames per iteration
#define NIT    16         // iterations
#define SPITCH 17         // specT row pitch in float2 (16 frames + 1 pad)

// XOR-swizzle: fold float2-index bits[5:4] into bank bits[3:2].
#define SW(i) ((i) ^ (((i) >> 2) & 12))

#define CFENCE() asm volatile("" ::: "memory")
// barrier that does NOT drain vmcnt: prefetch loads stay in flight
#define BAR() do { asm volatile("s_waitcnt lgkmcnt(0)" ::: "memory"); \
                   __builtin_amdgcn_s_barrier(); \
                   asm volatile("" ::: "memory"); } while (0)

__device__ __forceinline__ float2 cadd(float2 a, float2 b) { return make_float2(a.x + b.x, a.y + b.y); }
__device__ __forceinline__ float2 csub(float2 a, float2 b) { return make_float2(a.x - b.x, a.y - b.y); }
__device__ __forceinline__ float2 cmul(float2 a, float2 b) {
    return make_float2(a.x * b.x - a.y * b.y, a.x * b.y + a.y * b.x);
}
template <int SGN>
__device__ __forceinline__ float2 cmulsg(float2 w, float2 t) {
    if (SGN > 0) return make_float2(w.x * t.x - w.y * t.y, w.x * t.y + w.y * t.x);
    else         return make_float2(w.x * t.x + w.y * t.y, w.x * t.y - w.y * t.x);
}
template <int SGN>
__device__ __forceinline__ void bfly4(float2 z0, float2 z1, float2 z2, float2 z3,
                                      float2& o0, float2& o1, float2& o2, float2& o3,
                                      float2 w1, float2 w2, float2 w3) {
    float2 apc = cadd(z0, z2), amc = csub(z0, z2);
    float2 bpd = cadd(z1, z3), bmd = csub(z1, z3);
    float2 jb  = make_float2(-bmd.y, bmd.x);
    float2 t1, t3;
    if (SGN > 0) { t1 = csub(amc, jb); t3 = cadd(amc, jb); }
    else         { t1 = cadd(amc, jb); t3 = csub(amc, jb); }
    o0 = cadd(apc, bpd);
    o1 = cmulsg<SGN>(w1, t1);
    o2 = cmulsg<SGN>(w2, csub(apc, bpd));
    o3 = cmulsg<SGN>(w3, t3);
}
template <int SGN>
__device__ __forceinline__ void bfly4nt(float2 z0, float2 z1, float2 z2, float2 z3,
                                        float2& o0, float2& o1, float2& o2, float2& o3) {
    float2 apc = cadd(z0, z2), amc = csub(z0, z2);
    float2 bpd = cadd(z1, z3), bmd = csub(z1, z3);
    float2 jb  = make_float2(-bmd.y, bmd.x);
    o0 = cadd(apc, bpd);
    o2 = csub(apc, bpd);
    if (SGN > 0) { o1 = csub(amc, jb); o3 = cadd(amc, jb); }
    else         { o1 = cadd(amc, jb); o3 = csub(amc, jb); }
}

__device__ __forceinline__ float ftanh(float x) {
    float e = __expf(2.0f * x);
    return 1.0f - 2.0f * __builtin_amdgcn_rcpf(e + 1.0f);
}

// ---------------- kernel 1: channel mix + zero pad -------------------------
__global__ __launch_bounds__(512, 1) void mix_kernel(const float* __restrict__ x,
                                                     const float* __restrict__ mixer,
                                                     float* __restrict__ mixed) {
    __shared__ __align__(16) float xt[64][128];
    __shared__ __align__(16) float mx[64][64];
    int tid = threadIdx.x;
    int b   = blockIdx.y;
    int t0  = blockIdx.x * 128;

    if (t0 >= T_LEN) {   // zero-pad region [T, T_PAD)
        for (int f = tid; f < 8192; f += 512) {
            int d = f >> 7, tt = f & 127;
            mixed[((size_t)(b * C_CH + d)) * T_PAD + t0 + tt] = 0.0f;
        }
        return;
    }
    for (int f = tid; f < 4096; f += 512) reinterpret_cast<float*>(mx)[f] = mixer[f];
    for (int f4 = tid; f4 < 2048; f4 += 512) {
        int cc = f4 >> 5, tt4 = f4 & 31;
        *reinterpret_cast<float4*>(&xt[cc][tt4 * 4]) =
            *reinterpret_cast<const float4*>(&x[((size_t)(b * C_CH + cc)) * T_LEN + t0 + tt4 * 4]);
    }
    __syncthreads();

    int tp = tid & 63, grp = tid >> 6;
    int dbase = grp * 8;
    float2 acc[8];
#pragma unroll
    for (int i = 0; i < 8; ++i) acc[i] = make_float2(0.0f, 0.0f);
    for (int cc = 0; cc < 64; ++cc) {
        float2 xv = *reinterpret_cast<const float2*>(&xt[cc][2 * tp]);
        float4 m0 = *reinterpret_cast<const float4*>(&mx[cc][dbase + 0]);
        float4 m1 = *reinterpret_cast<const float4*>(&mx[cc][dbase + 4]);
        acc[0].x = fmaf(xv.x, m0.x, acc[0].x); acc[0].y = fmaf(xv.y, m0.x, acc[0].y);
        acc[1].x = fmaf(xv.x, m0.y, acc[1].x); acc[1].y = fmaf(xv.y, m0.y, acc[1].y);
        acc[2].x = fmaf(xv.x, m0.z, acc[2].x); acc[2].y = fmaf(xv.y, m0.z, acc[2].y);
        acc[3].x = fmaf(xv.x, m0.w, acc[3].x); acc[3].y = fmaf(xv.y, m0.w, acc[3].y);
        acc[4].x = fmaf(xv.x, m1.x, acc[4].x); acc[4].y = fmaf(xv.y, m1.x, acc[4].y);
        acc[5].x = fmaf(xv.x, m1.y, acc[5].x); acc[5].y = fmaf(xv.y, m1.y, acc[5].y);
        acc[6].x = fmaf(xv.x, m1.z, acc[6].x); acc[6].y = fmaf(xv.y, m1.z, acc[6].y);
        acc[7].x = fmaf(xv.x, m1.w, acc[7].x); acc[7].y = fmaf(xv.y, m1.w, acc[7].y);
    }
#pragma unroll
    for (int i = 0; i < 8; ++i)
        *reinterpret_cast<float2*>(&mixed[((size_t)(b * C_CH + dbase + i)) * T_PAD + t0 + 2 * tp]) = acc[i];
}

// -------- kernel 2: fused STFT -> scan -> iSTFT -> window -> OLA -> tanh ---
// 8 waves x 2 frames each (ILP-2): wave g handles frames it*16+g and it*16+g+8.
// r10 schedule/layout otherwise unchanged.
__global__ __launch_bounds__(512, 2) void stft_kernel(const float* __restrict__ mixed,
                                                      const float* __restrict__ transfer,
                                                      const float* __restrict__ gainp,
                                                      float* __restrict__ out) {
    __shared__ __align__(16) float2 buf[FPI][256];           // rows g (A) and g+8 (B)
    __shared__ __align__(16) float2 specT[2][K_ * SPITCH];   // bin-major, pitch 17
    __shared__ __align__(16) float  olab[FPI][264];          // row j read by frame j
    __shared__ __align__(16) float  tails[2][264];

    const int tid  = threadIdx.x;
    const int bc   = blockIdx.x;
    const int b    = bc >> 6, c = bc & 63;
    const int g    = tid >> 6, lane = tid & 63;

    const float* src = mixed + ((size_t)(b * C_CH + c)) * T_PAD;
    float*       dst = out   + ((size_t)(b * C_CH + c)) * T_LEN;

    // ---- prefetch frames g and g+8 (iteration 0)
    float2 pfA0, pfA1, pfA2, pfA3, pfB0, pfB1, pfB2, pfB3;
    {
        const float* fp = src + (size_t)g * STEP_;
        pfA0 = *reinterpret_cast<const float2*>(fp + 2 * lane);
        pfA1 = *reinterpret_cast<const float2*>(fp + 2 * (lane + 64));
        pfA2 = *reinterpret_cast<const float2*>(fp + 2 * (lane + 128));
        pfA3 = *reinterpret_cast<const float2*>(fp + 2 * (lane + 192));
        const float* fq = fp + (size_t)8 * STEP_;
        pfB0 = *reinterpret_cast<const float2*>(fq + 2 * lane);
        pfB1 = *reinterpret_cast<const float2*>(fq + 2 * (lane + 64));
        pfB2 = *reinterpret_cast<const float2*>(fq + 2 * (lane + 128));
        pfB3 = *reinterpret_cast<const float2*>(fq + 2 * (lane + 192));
    }

    // ---- per-lane constant twiddles (registers)
    const float TWO_PI = 6.2831853071795864f;
    float sn, cn;
    sincosf(TWO_PI * (float)lane / 256.0f, &sn, &cn);
    const float2 w1a = make_float2(cn, -sn), w2a = cmul(w1a, w1a), w3a = cmul(w2a, w1a);
    sincosf(TWO_PI * (float)(lane >> 2) / 64.0f, &sn, &cn);
    const float2 w1b = make_float2(cn, -sn), w2b = cmul(w1b, w1b), w3b = cmul(w2b, w1b);
    sincosf(TWO_PI * (float)(lane >> 4) / 16.0f, &sn, &cn);
    const float2 w1c = make_float2(cn, -sn), w2c = cmul(w1c, w1c), w3c = cmul(w2c, w1c);
    float2 wh[4];
#pragma unroll
    for (int qq = 0; qq < 4; ++qq) {
        sincosf(3.14159265358979f * (float)(lane + 64 * qq) / 256.0f, &sn, &cn);
        wh[qq] = make_float2(cn, -sn);
    }
#define HV(m) ((0.5f - 0.5f * cosf(TWO_PI * (float)(m) / 512.0f)) * (1.0f / 512.0f))
    const float h0 = HV(2 * lane),       h1 = HV(2 * lane + 1);
    const float h2 = HV(2 * lane + 128), h3 = HV(2 * lane + 129);
    const float h4 = HV(2 * lane + 256), h5 = HV(2 * lane + 257);
    const float h6 = HV(2 * lane + 384), h7 = HV(2 * lane + 385);
#undef HV

    // ---- loop-invariant LDS addresses (float2 index space; r10-verified)
    const int q2  = (lane & 3)  + ((lane >> 2) << 4);
    const int q3  = (lane & 15) + ((lane >> 4) << 6);
    const int swl = SW(lane);
    const int s1b = (4 * lane) ^ (lane & 12);
    const int sq2a = SW(q2);
    const int sq2b = SW(q2 + 4);
    const int sq2c = SW(q2 + 8);
    const int sq2d = SW(q2 + 12);
    const int sq3a = q3;
    const int sq3b = (q3 + 16) ^ 4;
    const int sq3c = (q3 + 32) ^ 8;
    const int sq3d = (q3 + 48) ^ 12;
    const int mm0 = SW((256 - lane) & 255);
    const int mm1 = SW(192 - lane);
    const int mm2 = SW(128 - lane);
    const int mm3 = SW(64 - lane);
    // specT column offsets: frame-in-iter = g (A) and g+8 (B)
    const int spwA = lane * SPITCH + g;
    const int spwB = spwA + 8;
    const int spmA = 256 * SPITCH + g - lane * SPITCH;
    const int spmB = spmA + 8;

    // ---- scan: waves 0-1 take 2 bins/lane (k, k+128); wave 2 lane 0 takes 256.
    int k1 = -1, k2 = -1;
    if (g < 2) { k1 = (g << 6) | lane; k2 = k1 + 128; }
    else if (g == 2 && lane == 0) { k1 = 256; }
    float tk1 = 0.0f, tk2 = 0.0f;
    float2 yc1 = make_float2(0.f, 0.f), yc2 = make_float2(0.f, 0.f);
    if (k1 >= 0) tk1 = transfer[c * K_ + k1];
    if (k2 >= 0) tk2 = transfer[c * K_ + k2];

    if (tid < 256) tails[0][tid] = 0.0f;
    const float gv = gainp[0];
    float2* binA = &buf[g][0];
    float2* binB = &buf[g + 8][0];
    BAR();

    for (int it = 0; it <= NIT; ++it) {
        const int sp = it & 1;
        // ================= forward: frames it*16+g and it*16+g+8 =================
        if (it < NIT) {
            float2 zA0 = pfA0, zA1 = pfA1, zA2 = pfA2, zA3 = pfA3;
            float2 zB0 = pfB0, zB1 = pfB1, zB2 = pfB2, zB3 = pfB3;
            if (it + 1 < NIT) {
                const float* fp = src + (size_t)((it + 1) * FPI + g) * STEP_;
                pfA0 = *reinterpret_cast<const float2*>(fp + 2 * lane);
                pfA1 = *reinterpret_cast<const float2*>(fp + 2 * (lane + 64));
                pfA2 = *reinterpret_cast<const float2*>(fp + 2 * (lane + 128));
                pfA3 = *reinterpret_cast<const float2*>(fp + 2 * (lane + 192));
                const float* fq = fp + (size_t)8 * STEP_;
                pfB0 = *reinterpret_cast<const float2*>(fq + 2 * lane);
                pfB1 = *reinterpret_cast<const float2*>(fq + 2 * (lane + 64));
                pfB2 = *reinterpret_cast<const float2*>(fq + 2 * (lane + 128));
                pfB3 = *reinterpret_cast<const float2*>(fq + 2 * (lane + 192));
            }
            float2 oA0, oA1, oA2, oA3, oB0, oB1, oB2, oB3;
            bfly4<1>(zA0, zA1, zA2, zA3, oA0, oA1, oA2, oA3, w1a, w2a, w3a);
            bfly4<1>(zB0, zB1, zB2, zB3, oB0, oB1, oB2, oB3, w1a, w2a, w3a);
            {
                float2* bw = binA + s1b;
                *reinterpret_cast<float4*>(bw)     = make_float4(oA0.x, oA0.y, oA1.x, oA1.y);
                *reinterpret_cast<float4*>(bw + 2) = make_float4(oA2.x, oA2.y, oA3.x, oA3.y);
                float2* bx = binB + s1b;
                *reinterpret_cast<float4*>(bx)     = make_float4(oB0.x, oB0.y, oB1.x, oB1.y);
                *reinterpret_cast<float4*>(bx + 2) = make_float4(oB2.x, oB2.y, oB3.x, oB3.y);
            }
            CFENCE();
            zA0 = binA[swl]; zA1 = binA[swl + 64]; zA2 = binA[swl + 128]; zA3 = binA[swl + 192];
            zB0 = binB[swl]; zB1 = binB[swl + 64]; zB2 = binB[swl + 128]; zB3 = binB[swl + 192];
            bfly4<1>(zA0, zA1, zA2, zA3, oA0, oA1, oA2, oA3, w1b, w2b, w3b);
            bfly4<1>(zB0, zB1, zB2, zB3, oB0, oB1, oB2, oB3, w1b, w2b, w3b);
            CFENCE();
            binA[sq2a] = oA0; binA[sq2b] = oA1; binA[sq2c] = oA2; binA[sq2d] = oA3;
            binB[sq2a] = oB0; binB[sq2b] = oB1; binB[sq2c] = oB2; binB[sq2d] = oB3;
            CFENCE();
            zA0 = binA[swl]; zA1 = binA[swl + 64]; zA2 = binA[swl + 128]; zA3 = binA[swl + 192];
            zB0 = binB[swl]; zB1 = binB[swl + 64]; zB2 = binB[swl + 128]; zB3 = binB[swl + 192];
            bfly4<1>(zA0, zA1, zA2, zA3, oA0, oA1, oA2, oA3, w1c, w2c, w3c);
            bfly4<1>(zB0, zB1, zB2, zB3, oB0, oB1, oB2, oB3, w1c, w2c, w3c);
            CFENCE();
            binA[sq3a] = oA0; binA[sq3b] = oA1; binA[sq3c] = oA2; binA[sq3d] = oA3;
            binB[sq3a] = oB0; binB[sq3b] = oB1; binB[sq3c] = oB2; binB[sq3d] = oB3;
            CFENCE();
            zA0 = binA[swl]; zA1 = binA[swl + 64]; zA2 = binA[swl + 128]; zA3 = binA[swl + 192];
            zB0 = binB[swl]; zB1 = binB[swl + 64]; zB2 = binB[swl + 128]; zB3 = binB[swl + 192];
            bfly4nt<1>(zA0, zA1, zA2, zA3, oA0, oA1, oA2, oA3);
            bfly4nt<1>(zB0, zB1, zB2, zB3, oB0, oB1, oB2, oB3);
            CFENCE();
            binA[swl] = oA0; binA[swl + 64] = oA1; binA[swl + 128] = oA2; binA[swl + 192] = oA3;
            binB[swl] = oB0; binB[swl + 64] = oB1; binB[swl + 128] = oB2; binB[swl + 192] = oB3;
            CFENCE();
            // Hermitian: u from regs, v mirrors from LDS; write specT cols g / g+8
            {
                float2 vA0 = binA[mm0], vA1 = binA[mm1], vA2 = binA[mm2], vA3 = binA[mm3];
                float2 vB0 = binB[mm0], vB1 = binB[mm1], vB2 = binB[mm2], vB3 = binB[mm3];
                float2 uuA[4] = {oA0, oA1, oA2, oA3}, vvA[4] = {vA0, vA1, vA2, vA3};
                float2 uuB[4] = {oB0, oB1, oB2, oB3}, vvB[4] = {vB0, vB1, vB2, vB3};
                float2* st = &specT[sp][0];
#pragma unroll
                for (int qq = 0; qq < 4; ++qq) {
                    float2 EA = make_float2(0.5f * (uuA[qq].x + vvA[qq].x),  0.5f * (uuA[qq].y - vvA[qq].y));
                    float2 OA = make_float2(0.5f * (uuA[qq].y + vvA[qq].y), -0.5f * (uuA[qq].x - vvA[qq].x));
                    st[spwA + 64 * SPITCH * qq] = cadd(EA, cmul(wh[qq], OA));
                    float2 EB = make_float2(0.5f * (uuB[qq].x + vvB[qq].x),  0.5f * (uuB[qq].y - vvB[qq].y));
                    float2 OB = make_float2(0.5f * (uuB[qq].y + vvB[qq].y), -0.5f * (uuB[qq].x - vvB[qq].x));
                    st[spwB + 64 * SPITCH * qq] = cadd(EB, cmul(wh[qq], OB));
                }
                if (lane == 0) {
                    st[256 * SPITCH + g]     = make_float2(oA0.x - oA0.y, 0.0f);
                    st[256 * SPITCH + g + 8] = make_float2(oB0.x - oB0.y, 0.0f);
                }
            }
        }
        BAR();   // B1: specT[sp] complete
        // ====== scan(it) on waves 0-2 (2 chains/lane) || inverse(it-1) ======
        if (it < NIT && k1 >= 0) {
            float2* s1p = &specT[sp][k1 * SPITCH];
            float2 va[8]; float2 y1 = yc1;
#pragma unroll
            for (int gg = 0; gg < 8; ++gg) va[gg] = s1p[gg];
            if (k2 >= 0) {
                float2* s2p = &specT[sp][k2 * SPITCH];
                float2 vb[8]; float2 y2 = yc2;
#pragma unroll
                for (int gg = 0; gg < 8; ++gg) vb[gg] = s2p[gg];
#pragma unroll
                for (int gg = 0; gg < 8; ++gg) {
                    y1.x = (va[gg].x + y1.x) * tk1; y1.y = (va[gg].y + y1.y) * tk1; s1p[gg] = y1;
                    y2.x = (vb[gg].x + y2.x) * tk2; y2.y = (vb[gg].y + y2.y) * tk2; s2p[gg] = y2;
                }
#pragma unroll
                for (int gg = 0; gg < 8; ++gg) { va[gg] = s1p[gg + 8]; vb[gg] = s2p[gg + 8]; }
#pragma unroll
                for (int gg = 0; gg < 8; ++gg) {
                    y1.x = (va[gg].x + y1.x) * tk1; y1.y = (va[gg].y + y1.y) * tk1; s1p[gg + 8] = y1;
                    y2.x = (vb[gg].x + y2.x) * tk2; y2.y = (vb[gg].y + y2.y) * tk2; s2p[gg + 8] = y2;
                }
                yc2 = y2;
            } else {
#pragma unroll
                for (int gg = 0; gg < 8; ++gg) {
                    y1.x = (va[gg].x + y1.x) * tk1; y1.y = (va[gg].y + y1.y) * tk1; s1p[gg] = y1;
                }
#pragma unroll
                for (int gg = 0; gg < 8; ++gg) va[gg] = s1p[gg + 8];
#pragma unroll
                for (int gg = 0; gg < 8; ++gg) {
                    y1.x = (va[gg].x + y1.x) * tk1; y1.y = (va[gg].y + y1.y) * tk1; s1p[gg + 8] = y1;
                }
            }
            yc1 = y1;
        }
        // ============ inverse + OLA for frames (it-1)*16 + g / +8 ============
        if (it > 0) {
            const float2* st = &specT[sp ^ 1][0];
            float2 oA0, oA1, oA2, oA3, oB0, oB1, oB2, oB3;
            {
                float2 iuA[4], isA[4], iuB[4], isB[4];
#pragma unroll
                for (int qq = 0; qq < 4; ++qq) {
                    iuA[qq] = st[spwA + 64 * SPITCH * qq];
                    isA[qq] = st[spmA - 64 * SPITCH * qq];
                    iuB[qq] = st[spwB + 64 * SPITCH * qq];
                    isB[qq] = st[spmB - 64 * SPITCH * qq];
                }
                float2 zzA[4], zzB[4];
#pragma unroll
                for (int qq = 0; qq < 4; ++qq) {
                    float2 AA  = make_float2(iuA[qq].x + isA[qq].x, iuA[qq].y - isA[qq].y);
                    float2 DA  = make_float2(iuA[qq].x - isA[qq].x, iuA[qq].y + isA[qq].y);
                    float2 BvA = cmulsg<-1>(wh[qq], DA);
                    zzA[qq] = make_float2(AA.x - BvA.y, AA.y + BvA.x);
                    float2 AB  = make_float2(iuB[qq].x + isB[qq].x, iuB[qq].y - isB[qq].y);
                    float2 DB  = make_float2(iuB[qq].x - isB[qq].x, iuB[qq].y + isB[qq].y);
                    float2 BvB = cmulsg<-1>(wh[qq], DB);
                    zzB[qq] = make_float2(AB.x - BvB.y, AB.y + BvB.x);
                }
                bfly4<-1>(zzA[0], zzA[1], zzA[2], zzA[3], oA0, oA1, oA2, oA3, w1a, w2a, w3a);
                bfly4<-1>(zzB[0], zzB[1], zzB[2], zzB[3], oB0, oB1, oB2, oB3, w1a, w2a, w3a);
            }
            {
                float2* bw = binA + s1b;
                *reinterpret_cast<float4*>(bw)     = make_float4(oA0.x, oA0.y, oA1.x, oA1.y);
                *reinterpret_cast<float4*>(bw + 2) = make_float4(oA2.x, oA2.y, oA3.x, oA3.y);
                float2* bx = binB + s1b;
                *reinterpret_cast<float4*>(bx)     = make_float4(oB0.x, oB0.y, oB1.x, oB1.y);
                *reinterpret_cast<float4*>(bx + 2) = make_float4(oB2.x, oB2.y, oB3.x, oB3.y);
            }
            CFENCE();
            float2 zA0 = binA[swl], zA1 = binA[swl + 64], zA2 = binA[swl + 128], zA3 = binA[swl + 192];
            float2 zB0 = binB[swl], zB1 = binB[swl + 64], zB2 = binB[swl + 128], zB3 = binB[swl + 192];
            bfly4<-1>(zA0, zA1, zA2, zA3, oA0, oA1, oA2, oA3, w1b, w2b, w3b);
            bfly4<-1>(zB0, zB1, zB2, zB3, oB0, oB1, oB2, oB3, w1b, w2b, w3b);
            CFENCE();
            binA[sq2a] = oA0; binA[sq2b] = oA1; binA[sq2c] = oA2; binA[sq2d] = oA3;
            binB[sq2a] = oB0; binB[sq2b] = oB1; binB[sq2c] = oB2; binB[sq2d] = oB3;
            CFENCE();
            zA0 = binA[swl]; zA1 = binA[swl + 64]; zA2 = binA[swl + 128]; zA3 = binA[swl + 192];
            zB0 = binB[swl]; zB1 = binB[swl + 64]; zB2 = binB[swl + 128]; zB3 = binB[swl + 192];
            bfly4<-1>(zA0, zA1, zA2, zA3, oA0, oA1, oA2, oA3, w1c, w2c, w3c);
            bfly4<-1>(zB0, zB1, zB2, zB3, oB0, oB1, oB2, oB3, w1c, w2c, w3c);
            CFENCE();
            binA[sq3a] = oA0; binA[sq3b] = oA1; binA[sq3c] = oA2; binA[sq3d] = oA3;
            binB[sq3a] = oB0; binB[sq3b] = oB1; binB[sq3c] = oB2; binB[sq3d] = oB3;
            CFENCE();
            zA0 = binA[swl]; zA1 = binA[swl + 64]; zA2 = binA[swl + 128]; zA3 = binA[swl + 192];
            zB0 = binB[swl]; zB1 = binB[swl + 64]; zB2 = binB[swl + 128]; zB3 = binB[swl + 192];
            bfly4nt<-1>(zA0, zA1, zA2, zA3, oA0, oA1, oA2, oA3);
            bfly4nt<-1>(zB0, zB1, zB2, zB3, oB0, oB1, oB2, oB3);
            // publish windowed second halves: frame g -> olab[g+1]; frame g+8 -> olab[g+9] / tails
            {
                float2 shA0 = make_float2(oA2.x * h4, oA2.y * h5);
                float2 shA1 = make_float2(oA3.x * h6, oA3.y * h7);
                float* wrowA = olab[g + 1];
                *reinterpret_cast<float2*>(&wrowA[2 * lane])       = shA0;
                *reinterpret_cast<float2*>(&wrowA[2 * lane + 128]) = shA1;
                float2 shB0 = make_float2(oB2.x * h4, oB2.y * h5);
                float2 shB1 = make_float2(oB3.x * h6, oB3.y * h7);
                float* wrowB = (g == NWV - 1) ? tails[it & 1] : olab[g + 9];
                *reinterpret_cast<float2*>(&wrowB[2 * lane])       = shB0;
                *reinterpret_cast<float2*>(&wrowB[2 * lane + 128]) = shB1;
            }
            BAR();   // B2: neighbor halves visible, scan done
            {
                const float* prowA = (g == 0) ? tails[(it - 1) & 1] : olab[g];
                float2 pA0 = *reinterpret_cast<const float2*>(&prowA[2 * lane]);
                float2 pA1 = *reinterpret_cast<const float2*>(&prowA[2 * lane + 128]);
                const float* prowB = olab[g + 8];
                float2 pB0 = *reinterpret_cast<const float2*>(&prowB[2 * lane]);
                float2 pB1 = *reinterpret_cast<const float2*>(&prowB[2 * lane + 128]);
                float2 rA0 = make_float2(ftanh((oA0.x * h0 + pA0.x) * gv),
                                         ftanh((oA0.y * h1 + pA0.y) * gv));
                float2 rA1 = make_float2(ftanh((oA1.x * h2 + pA1.x) * gv),
                                         ftanh((oA1.y * h3 + pA1.y) * gv));
                float2 rB0 = make_float2(ftanh((oB0.x * h0 + pB0.x) * gv),
                                         ftanh((oB0.y * h1 + pB0.y) * gv));
                float2 rB1 = make_float2(ftanh((oB1.x * h2 + pB1.x) * gv),
                                         ftanh((oB1.y * h3 + pB1.y) * gv));
                float* dpA = dst + (size_t)((it - 1) * FPI + g) * STEP_;
                *reinterpret_cast<float2*>(&dpA[2 * lane])       = rA0;
                *reinterpret_cast<float2*>(&dpA[2 * lane + 128]) = rA1;
                float* dpB = dpA + (size_t)8 * STEP_;
                *reinterpret_cast<float2*>(&dpB[2 * lane])       = rB0;
                *reinterpret_cast<float2*>(&dpB[2 * lane + 128]) = rB1;
            }
        }
    }
}

extern "C" void kernel_launch(void* const* d_in, const int* in_sizes, int n_in,
                              void* d_out, int out_size, void* d_ws, size_t ws_size,
                              hipStream_t stream) {
    (void)in_sizes; (void)n_in; (void)out_size; (void)ws_size;
    const float* x        = (const float*)d_in[0];
    const float* mixer    = (const float*)d_in[1];
    const float* transfer = (const float*)d_in[2];
    const float* gain     = (const float*)d_in[3];
    float* out   = (float*)d_out;
    float* mixed = (float*)d_ws;   // (B, C, T_PAD) f32 = 67.4 MB

    dim3 gmix(T_PAD / 128, 4);
    mix_kernel<<<gmix, 512, 0, stream>>>(x, mixer, mixed);
    stft_kernel<<<256, 512, 0, stream>>>(mixed, transfer, gain, out);
}